// Round 16
// baseline (46.150 us; speedup 1.0000x reference)
//
#include <hip/hip_runtime.h>
#include <hip/hip_bf16.h>

#define T_TOKENS 2048
#define DIM 256
#define NLEV 8
#define MAXU 512

using bf16x8 = __attribute__((ext_vector_type(8))) short;
using f32x4  = __attribute__((ext_vector_type(4))) float;

__device__ __forceinline__ unsigned short f2bf(float f) {
    union { float f; unsigned u; } v; v.f = f;
    unsigned r = v.u + 0x7FFFu + ((v.u >> 16) & 1u);   // RNE
    return (unsigned short)(r >> 16);
}
__device__ __forceinline__ float bf2f(unsigned short h) {
    union { unsigned u; float f; } w; w.u = (unsigned)h << 16; return w.f;
}

// ---------------- Kernel 1: routing (exact fp32) + x -> bf16 conversion ----------------
__global__ __launch_bounds__(256) void route_kernel(
    const float* __restrict__ x, const float* __restrict__ w1s,
    const float* __restrict__ b1s,
    float* __restrict__ pw, int* __restrict__ pc,
    unsigned short* __restrict__ xbf)
{
    int wave = threadIdx.x >> 6;
    int lane = threadIdx.x & 63;
    int t = blockIdx.x * 4 + wave;    // grid = 512 -> t < 2048

    const float4 xv = *reinterpret_cast<const float4*>(x + (size_t)t * DIM + lane * 4);

    ushort4 xb;
    xb.x = f2bf(xv.x); xb.y = f2bf(xv.y); xb.z = f2bf(xv.z); xb.w = f2bf(xv.w);
    *reinterpret_cast<ushort4*>(xbf + (size_t)t * DIM + lane * 4) = xb;

    int p = 1;
    float keep = 0.0f;
    #pragma unroll
    for (int lvl = 0; lvl < NLEV; ++lvl) {
        int node = p - 1;
        const float4 wv = *reinterpret_cast<const float4*>(w1s + (size_t)node * DIM + lane * 4);
        float s = xv.x * wv.x + xv.y * wv.y + xv.z * wv.z + xv.w * wv.w;
        #pragma unroll
        for (int off = 32; off; off >>= 1) s += __shfl_xor(s, off);
        float score = s + b1s[node];
        float a = fabsf(score);
        float g = a * 0.5f * (1.0f + erff(a * 0.70710678118654752f));  // exact GELU
        if (lane == lvl) keep = g;
        int choice = (score > 0.0f) ? 1 : 0;   // sign(0)->choice 0 matches ref
        p = 2 * p + choice;
    }
    if (lane < NLEV) pw[(size_t)t * NLEV + lane] = keep;
    if (lane == 0) pc[t] = p;
}

// ---------------- Kernel 2: counting sort + 64-chunk unit enumeration (1 block) ----------------
__global__ __launch_bounds__(256) void sort_kernel(
    const int* __restrict__ pc,
    int* __restrict__ order, unsigned* __restrict__ units, int* __restrict__ ucount)
{
    __shared__ int hist[256];
    __shared__ int offs[256];
    __shared__ int cums[257];
    __shared__ int wpart[4];
    int tid = threadIdx.x;
    hist[tid] = 0;
    __syncthreads();

    int myPc[8];
    #pragma unroll
    for (int i = 0; i < 8; ++i) {
        int t = tid * 8 + i;
        myPc[i] = pc[t];
        atomicAdd(&hist[myPc[i] - 256], 1);
    }
    __syncthreads();

    if (tid < 64) {
        int lane = tid;
        int v0 = hist[lane * 4 + 0], v1 = hist[lane * 4 + 1];
        int v2 = hist[lane * 4 + 2], v3 = hist[lane * 4 + 3];
        int sum = v0 + v1 + v2 + v3;
        int scan = sum;
        #pragma unroll
        for (int off = 1; off < 64; off <<= 1) {
            int n = __shfl_up(scan, off);
            if (lane >= off) scan += n;
        }
        int excl = scan - sum;
        offs[lane * 4 + 0] = excl;
        offs[lane * 4 + 1] = excl + v0;
        offs[lane * 4 + 2] = excl + v0 + v1;
        offs[lane * 4 + 3] = excl + v0 + v1 + v2;
    }
    __syncthreads();

    cums[tid] = offs[tid];
    if (tid == 0) cums[256] = T_TOKENS;
    __syncthreads();

    #pragma unroll
    for (int i = 0; i < 8; ++i) {
        int t = tid * 8 + i;
        int bin = myPc[i] - 256;
        int pos = atomicAdd(&offs[bin], 1);
        order[pos] = t;
    }

    int nch = 0, s = 0, e = 0, l = 0;
    if (tid < 255) {
        int q = tid + 1;
        l = 31 - __clz(q);
        int shift = 8 - l;
        int lo = (q << shift) - 256;
        int hi = ((q + 1) << shift) - 256;
        s = cums[lo];
        e = cums[hi];
        nch = (e - s + 63) >> 6;
    }
    int lane = tid & 63, w = tid >> 6;
    int scan = nch;
    #pragma unroll
    for (int off = 1; off < 64; off <<= 1) {
        int n = __shfl_up(scan, off);
        if (lane >= off) scan += n;
    }
    if (lane == 63) wpart[w] = scan;
    __syncthreads();
    int pre = 0;
    for (int k = 0; k < w; ++k) pre += wpart[k];
    int base = pre + scan - nch;
    for (int j = 0; j < nch; ++j) {
        int st = s + j * 64;
        int c = e - st; if (c > 64) c = 64;
        units[base + j] = (unsigned)tid | ((unsigned)l << 8) |
                          ((unsigned)st << 11) | ((unsigned)c << 22);
    }
    if (tid == 255) *ucount = pre + scan;
}

// ---------------- Kernel 3: async-staged per-unit GEMM (global_load_lds + counted vmcnt) ----------------
// Block = (unit<=64 tok, col-half 128), XCD-chunk-swizzled so same-node blocks share
// an XCD's L2 (redundant chunk re-fetch of B becomes L2-hit). Schedule as r15 (proven).
__global__ __launch_bounds__(256, 4) void out_kernel(
    const unsigned short* __restrict__ xbf, const float* __restrict__ w2s,
    const float* __restrict__ b2s, const float* __restrict__ pw,
    const int* __restrict__ order, const unsigned* __restrict__ units,
    const int* __restrict__ ucount, unsigned short* __restrict__ lvlbuf)
{
    __shared__ float Bs[2][32][128];   // 2 x 16 KiB, linear (global_load_lds dest)

    // bijective XCD-chunked swizzle: 1024 blocks = 8 XCDs x 128; consecutive L
    // (same node's units) land on one XCD.
    int bid = blockIdx.x;
    int L = (bid & 7) * 128 + (bid >> 3);
    int u = L >> 1;
    int ch = L & 1;
    if (u >= *ucount) return;          // uniform exit BEFORE any barrier
    unsigned d = units[u];
    int node  = (int)(d & 255u);
    int lvl   = (int)((d >> 8) & 7u);
    int start = (int)((d >> 11) & 2047u);
    int cnt   = (int)((d >> 22) & 127u);

    int tid = threadIdx.x;
    int wv = tid >> 6, lane = tid & 63;
    int l15 = lane & 15, kg = lane >> 4;

    int tok[4];
    #pragma unroll
    for (int m = 0; m < 4; ++m) {
        int r = m * 16 + l15;
        tok[m] = order[start + (r < cnt ? r : cnt - 1)];
    }

    const float* w2n = w2s + ((size_t)node << 16) + ch * 128;
    int srow = wv * 8 + (lane >> 5);     // staging row within panel (+= i*2)
    int scol = (lane & 31) * 4;          // staging col (floats)

    auto STAGE = [&](int p, int q) {
        #pragma unroll
        for (int i = 0; i < 4; ++i) {
            const float* src = w2n + (size_t)(p * 32 + srow + i * 2) * 256 + scol;
            float* dst = &Bs[q][wv * 8 + i * 2][0];   // wave-uniform base; HW adds lane*16
            __builtin_amdgcn_global_load_lds(
                (const __attribute__((address_space(1))) void*)src,
                (__attribute__((address_space(3))) void*)dst, 16, 0, 0);
        }
    };
    auto LOADA = [&](int p, bf16x8 (&a)[4]) {
        #pragma unroll
        for (int m = 0; m < 4; ++m)
            a[m] = *reinterpret_cast<const bf16x8*>(xbf + ((size_t)tok[m] << 8) + p * 32 + kg * 8);
    };

    f32x4 acc[4][2];
    #pragma unroll
    for (int m = 0; m < 4; ++m) {
        acc[m][0] = (f32x4){0.f, 0.f, 0.f, 0.f};
        acc[m][1] = (f32x4){0.f, 0.f, 0.f, 0.f};
    }

    auto COMPUTE = [&](int q, const bf16x8 (&a)[4]) {
        bf16x8 bf[2];
        #pragma unroll
        for (int nb = 0; nb < 2; ++nb) {
            bf16x8 v;
            #pragma unroll
            for (int i = 0; i < 8; ++i)
                v[i] = (short)f2bf(Bs[q][kg * 8 + i][wv * 32 + nb * 16 + l15]);
            bf[nb] = v;
        }
        #pragma unroll
        for (int m = 0; m < 4; ++m) if (m * 16 < cnt)
            #pragma unroll
            for (int nb = 0; nb < 2; ++nb)
                acc[m][nb] = __builtin_amdgcn_mfma_f32_16x16x32_bf16(a[m], bf[nb], acc[m][nb], 0, 0, 0);
    };

    bf16x8 aP[4], aQ[4];

    STAGE(0, 0);
    LOADA(0, aP);
    STAGE(1, 1);
    asm volatile("s_waitcnt vmcnt(4)" ::: "memory");
    __builtin_amdgcn_s_barrier();
    __builtin_amdgcn_sched_barrier(0);

    #pragma unroll
    for (int p = 0; p < 8; ++p) {
        if (p & 1) COMPUTE(1, aQ); else COMPUTE(0, aP);
        __builtin_amdgcn_s_barrier();          // all waves done reading Bs[p&1]
        if (p < 6) {
            if (p & 1) LOADA(p + 1, aP); else LOADA(p + 1, aQ);
            STAGE(p + 2, p & 1);               // overwrite just-consumed buffer
            asm volatile("s_waitcnt vmcnt(4)" ::: "memory");
        } else if (p == 6) {
            LOADA(7, aQ);
            asm volatile("s_waitcnt vmcnt(0)" ::: "memory");
        }
        __builtin_amdgcn_s_barrier();
        __builtin_amdgcn_sched_barrier(0);
    }

    // epilogue: lvlbuf[lvl][tok][col] = bf16( pw[tok][lvl] * (acc + bias) )
    float bias[2];
    #pragma unroll
    for (int nb = 0; nb < 2; ++nb)
        bias[nb] = b2s[((size_t)node << 8) + ch * 128 + wv * 32 + nb * 16 + l15];

    unsigned short* dst = lvlbuf + ((size_t)lvl << 19);

    #pragma unroll
    for (int m = 0; m < 4; ++m) if (m * 16 < cnt) {
        #pragma unroll
        for (int j = 0; j < 4; ++j) {
            int r = m * 16 + kg * 4 + j;
            if (r < cnt) {
                int t = __shfl(tok[m], kg * 4 + j);
                float w = pw[(size_t)t * NLEV + lvl];
                #pragma unroll
                for (int nb = 0; nb < 2; ++nb)
                    dst[((size_t)t << 8) + ch * 128 + wv * 32 + nb * 16 + l15] =
                        f2bf(w * (acc[m][nb][j] + bias[nb]));
            }
        }
    }
}

// ---------------- Kernel 4: reduce 8 bf16 level-buffers -> fp32 out ----------------
__global__ __launch_bounds__(256) void reduce_kernel(
    const unsigned short* __restrict__ lvlbuf, float* __restrict__ out)
{
    int idx = blockIdx.x * 256 + threadIdx.x;          // ushort4 index, < 131072
    const ushort4* lb = reinterpret_cast<const ushort4*>(lvlbuf);
    float4 s = {0.f, 0.f, 0.f, 0.f};
    #pragma unroll
    for (int l = 0; l < NLEV; ++l) {
        ushort4 v = lb[(size_t)l * 131072 + idx];
        s.x += bf2f(v.x); s.y += bf2f(v.y); s.z += bf2f(v.z); s.w += bf2f(v.w);
    }
    reinterpret_cast<float4*>(out)[idx] = s;
}

extern "C" void kernel_launch(void* const* d_in, const int* in_sizes, int n_in,
                              void* d_out, int out_size, void* d_ws, size_t ws_size,
                              hipStream_t stream) {
    const float* x   = (const float*)d_in[0];
    const float* w1s = (const float*)d_in[1];
    const float* b1s = (const float*)d_in[2];
    const float* w2s = (const float*)d_in[3];
    const float* b2s = (const float*)d_in[4];
    float* out = (float*)d_out;

    float* pw            = (float*)d_ws;                          // 64 KB
    int* pc              = (int*)(pw + T_TOKENS * NLEV);          // 8 KB
    int* order           = pc + T_TOKENS;                         // 8 KB
    unsigned* units      = (unsigned*)(order + T_TOKENS);         // 2 KB
    int* ucount          = (int*)(units + MAXU);                  // 4 B
    unsigned short* xbf  = (unsigned short*)((char*)d_ws + (256 << 10));  // 1 MB
    unsigned short* lvlbuf = (unsigned short*)((char*)d_ws + (2 << 20)); // 8 MB bf16

    route_kernel<<<T_TOKENS / 4, 256, 0, stream>>>(x, w1s, b1s, pw, pc, xbf);
    sort_kernel<<<1, 256, 0, stream>>>(pc, order, units, ucount);
    out_kernel<<<2 * MAXU, 256, 0, stream>>>(xbf, w2s, b2s, pw, order, units, ucount, lvlbuf);
    reduce_kernel<<<512, 256, 0, stream>>>(lvlbuf, out);
}